// Round 1
// baseline (34848.767 us; speedup 1.0000x reference)
//
#include <hip/hip_runtime.h>
#include <hip/hip_bf16.h>

#define NW 4
#define NST 100
#define TT 128
#define II 256
#define HH 1024
#define H3 3072

__device__ __forceinline__ float sigf(float x) { return 1.0f / (1.0f + expf(-x)); }

// ---------------- zero init ----------------
__global__ void zero_k(float* a, int n) {
    int i = blockIdx.x * 256 + threadIdx.x;
    if (i < n) a[i] = 0.0f;
}

// ---------------- encoder GRU step (all 4 weeks), fused input+hidden proj + gates ----
// grid: (32 j-tiles, 2 m-tiles, 4 weeks), block 256 (tx=j 16x2, ty=m 16x4)
__global__ __launch_bounds__(256) void enc_step_k(
    const float* __restrict__ x0, const float* __restrict__ x1,
    const float* __restrict__ x2, const float* __restrict__ x3,
    const float* __restrict__ Wih, const float* __restrict__ Whh,
    const float* __restrict__ bih, const float* __restrict__ bhh,
    const float* __restrict__ hin, float* __restrict__ hout,
    __hip_bfloat16* __restrict__ seq, int t)
{
    int j0 = blockIdx.x * 32;
    int m0 = blockIdx.y * 64;
    int w  = blockIdx.z;
    const float* xw = (w == 0) ? x0 : (w == 1) ? x1 : (w == 2) ? x2 : x3;
    const float* Wh = Whh + (size_t)w * H3 * HH;
    const float* Wi = Wih + (size_t)w * H3 * II;
    const float* bi = bih + (size_t)w * H3;
    const float* bh = bhh + (size_t)w * H3;
    const float* hb = hin + (size_t)w * 128 * HH;
    float* ho = hout + (size_t)w * 128 * HH;

    __shared__ float hs[16][64];
    __shared__ float ws[3][16][32];
    int tid = threadIdx.x, tx = tid & 15, ty = tid >> 4;

    float accH[3][4][2] = {{{0.f}}};
    float accX[3][4][2] = {{{0.f}}};

    // hidden projection K=1024
    for (int k0 = 0; k0 < HH; k0 += 16) {
        __syncthreads();
        for (int q = tid; q < 1024; q += 256) {
            int kk = q & 15, m = q >> 4;
            hs[kk][m] = hb[(size_t)(m0 + m) * HH + k0 + kk];
        }
        for (int q = tid; q < 1536; q += 256) {
            int kk = q & 15, jj = (q >> 4) & 31, g = q >> 9;
            ws[g][kk][jj] = Wh[(size_t)(g * HH + j0 + jj) * HH + k0 + kk];
        }
        __syncthreads();
        #pragma unroll
        for (int kk = 0; kk < 16; kk++) {
            float4 hv = *(const float4*)&hs[kk][ty * 4];
            #pragma unroll
            for (int g = 0; g < 3; g++) {
                float2 wv = *(const float2*)&ws[g][kk][tx * 2];
                accH[g][0][0] += hv.x * wv.x; accH[g][0][1] += hv.x * wv.y;
                accH[g][1][0] += hv.y * wv.x; accH[g][1][1] += hv.y * wv.y;
                accH[g][2][0] += hv.z * wv.x; accH[g][2][1] += hv.z * wv.y;
                accH[g][3][0] += hv.w * wv.x; accH[g][3][1] += hv.w * wv.y;
            }
        }
    }
    // input projection K=256
    for (int k0 = 0; k0 < II; k0 += 16) {
        __syncthreads();
        for (int q = tid; q < 1024; q += 256) {
            int kk = q & 15, m = q >> 4;
            int mm = m0 + m;
            hs[kk][m] = (mm < NST) ? xw[(size_t)mm * TT * II + (size_t)t * II + k0 + kk] : 0.f;
        }
        for (int q = tid; q < 1536; q += 256) {
            int kk = q & 15, jj = (q >> 4) & 31, g = q >> 9;
            ws[g][kk][jj] = Wi[(size_t)(g * HH + j0 + jj) * II + k0 + kk];
        }
        __syncthreads();
        #pragma unroll
        for (int kk = 0; kk < 16; kk++) {
            float4 hv = *(const float4*)&hs[kk][ty * 4];
            #pragma unroll
            for (int g = 0; g < 3; g++) {
                float2 wv = *(const float2*)&ws[g][kk][tx * 2];
                accX[g][0][0] += hv.x * wv.x; accX[g][0][1] += hv.x * wv.y;
                accX[g][1][0] += hv.y * wv.x; accX[g][1][1] += hv.y * wv.y;
                accX[g][2][0] += hv.z * wv.x; accX[g][2][1] += hv.z * wv.y;
                accX[g][3][0] += hv.w * wv.x; accX[g][3][1] += hv.w * wv.y;
            }
        }
    }
    // epilogue: gates
    #pragma unroll
    for (int r = 0; r < 4; r++) {
        int m = m0 + ty * 4 + r;
        #pragma unroll
        for (int c = 0; c < 2; c++) {
            int j = j0 + tx * 2 + c;
            float xr = accX[0][r][c] + bi[j];
            float hr = accH[0][r][c] + bh[j];
            float xz = accX[1][r][c] + bi[HH + j];
            float hz = accH[1][r][c] + bh[HH + j];
            float xn = accX[2][r][c] + bi[2 * HH + j];
            float hn = accH[2][r][c] + bh[2 * HH + j];
            float rg = sigf(xr + hr);
            float zg = sigf(xz + hz);
            float ng = tanhf(xn + rg * hn);
            float hv = (1.f - zg) * ng + zg * hb[(size_t)m * HH + j];
            ho[(size_t)m * HH + j] = hv;
            if (m < NST)
                seq[(((size_t)w * NST + m) * TT + t) * HH + j] = __float2bfloat16(hv);
        }
    }
}

// ---------------- encoder time-attention ----------------
// grid: (8 d-chunks, 100 n, 4 w), block 256. Writes wex[w][n][d].
__global__ __launch_bounds__(256) void att1_k(
    const __hip_bfloat16* __restrict__ seq, const float* __restrict__ attW,
    const float* __restrict__ attb, float* __restrict__ wex)
{
    int d0 = blockIdx.x * 128;
    int n  = blockIdx.y;
    int w  = blockIdx.z;
    __shared__ __hip_bfloat16 S[128][128];  // [t][d]
    __shared__ float PM[16][136];
    int tid = threadIdx.x;
    const __hip_bfloat16* sp = seq + ((size_t)(w * NST + n) * TT) * HH + d0;
    for (int q = tid; q < 128 * 128; q += 256) {
        int t = q >> 7, d = q & 127;
        S[t][d] = sp[(size_t)t * HH + d];
    }
    __syncthreads();
    int tx = tid & 15, ty = tid >> 4;
    const float* Wg = attW + (size_t)w * TT * TT;
    float acc[8][8];
    #pragma unroll
    for (int i = 0; i < 8; i++) {
        float b = attb[w * TT + ty * 8 + i];
        for (int j = 0; j < 8; j++) acc[i][j] = b;
    }
    for (int t = 0; t < 128; t++) {
        float wv[8], sv[8];
        #pragma unroll
        for (int i = 0; i < 8; i++) wv[i] = Wg[(ty * 8 + i) * TT + t];
        #pragma unroll
        for (int j = 0; j < 8; j++) sv[j] = __bfloat162float(S[t][tx * 8 + j]);
        #pragma unroll
        for (int i = 0; i < 8; i++)
            #pragma unroll
            for (int j = 0; j < 8; j++) acc[i][j] += wv[i] * sv[j];
    }
    // softmax over t' (rows), distributed over ty groups
    float cmax[8], csum[8];
    #pragma unroll
    for (int j = 0; j < 8; j++) {
        float m = acc[0][j];
        for (int i = 1; i < 8; i++) m = fmaxf(m, acc[i][j]);
        PM[ty][tx * 8 + j] = m;
    }
    __syncthreads();
    #pragma unroll
    for (int j = 0; j < 8; j++) {
        float m = -1e30f;
        for (int yy = 0; yy < 16; yy++) m = fmaxf(m, PM[yy][tx * 8 + j]);
        cmax[j] = m;
    }
    __syncthreads();
    #pragma unroll
    for (int j = 0; j < 8; j++) {
        float s = 0.f;
        for (int i = 0; i < 8; i++) { acc[i][j] = expf(acc[i][j] - cmax[j]); s += acc[i][j]; }
        PM[ty][tx * 8 + j] = s;
    }
    __syncthreads();
    #pragma unroll
    for (int j = 0; j < 8; j++) {
        float s = 0.f;
        for (int yy = 0; yy < 16; yy++) s += PM[yy][tx * 8 + j];
        csum[j] = s;
    }
    __syncthreads();
    #pragma unroll
    for (int j = 0; j < 8; j++) {
        float o = 0.f;
        for (int i = 0; i < 8; i++) o += acc[i][j] * __bfloat162float(S[ty * 8 + i][tx * 8 + j]);
        PM[ty][tx * 8 + j] = o;
    }
    __syncthreads();
    if (ty == 0) {
        #pragma unroll
        for (int j = 0; j < 8; j++) {
            float o = 0.f;
            for (int yy = 0; yy < 16; yy++) o += PM[yy][tx * 8 + j];
            wex[((size_t)w * NST + n) * HH + d0 + tx * 8 + j] = o / csum[j];
        }
    }
}

// ---------------- generic fp32 GEMM: C[m][n] = sum_k A[m][k]*B[n][k] (+bias, relu) ----
template <int RELU>
__global__ __launch_bounds__(256) void gemm_tn_k(
    const float* __restrict__ A, const float* __restrict__ B,
    const float* __restrict__ bias, float* __restrict__ C, int M, int N, int K)
{
    int n0 = blockIdx.x * 64, m0 = blockIdx.y * 64;
    __shared__ float As[16][64], Bs[16][64];
    int tid = threadIdx.x, tx = tid & 15, ty = tid >> 4;
    float acc[4][4] = {{0.f}};
    for (int k0 = 0; k0 < K; k0 += 16) {
        __syncthreads();
        for (int q = tid; q < 1024; q += 256) {
            int kk = q & 15, r = q >> 4;
            int m = m0 + r, nn = n0 + r;
            As[kk][r] = (m < M) ? A[(size_t)m * K + k0 + kk] : 0.f;
            Bs[kk][r] = (nn < N) ? B[(size_t)nn * K + k0 + kk] : 0.f;
        }
        __syncthreads();
        #pragma unroll
        for (int kk = 0; kk < 16; kk++) {
            float4 av = *(const float4*)&As[kk][ty * 4];
            float4 bv = *(const float4*)&Bs[kk][tx * 4];
            float a[4] = {av.x, av.y, av.z, av.w};
            float b[4] = {bv.x, bv.y, bv.z, bv.w};
            #pragma unroll
            for (int r = 0; r < 4; r++)
                #pragma unroll
                for (int c = 0; c < 4; c++) acc[r][c] += a[r] * b[c];
        }
    }
    #pragma unroll
    for (int r = 0; r < 4; r++) {
        int m = m0 + ty * 4 + r;
        if (m >= M) continue;
        #pragma unroll
        for (int c = 0; c < 4; c++) {
            int nn = n0 + tx * 4 + c;
            if (nn >= N) continue;
            float v = acc[r][c] + (bias ? bias[nn] : 0.f);
            if (RELU) v = fmaxf(v, 0.f);
            C[(size_t)m * N + nn] = v;
        }
    }
}

// ---------------- weekly GRU step: batch 4, wave per j ----------------
__global__ __launch_bounds__(256) void wk_step_k(
    const float* __restrict__ gxw, const float* __restrict__ Whh,
    const float* __restrict__ bhh, const float* __restrict__ hin,
    float* __restrict__ hout, float* __restrict__ we2, int t)
{
    int j = blockIdx.x * 4 + (threadIdx.x >> 6);
    int lane = threadIdx.x & 63;
    float acc[4][3] = {{0.f}};
    for (int k = lane; k < HH; k += 64) {
        float wr = Whh[(size_t)j * HH + k];
        float wz = Whh[(size_t)(HH + j) * HH + k];
        float wn = Whh[(size_t)(2 * HH + j) * HH + k];
        #pragma unroll
        for (int b = 0; b < 4; b++) {
            float hv = hin[b * HH + k];
            acc[b][0] += hv * wr; acc[b][1] += hv * wz; acc[b][2] += hv * wn;
        }
    }
    #pragma unroll
    for (int b = 0; b < 4; b++)
        #pragma unroll
        for (int g = 0; g < 3; g++)
            for (int o = 32; o; o >>= 1) acc[b][g] += __shfl_down(acc[b][g], o);
    if (lane == 0) {
        for (int b = 0; b < 4; b++) {
            const float* gx = gxw + ((size_t)b * NST + t) * H3;
            float hr = acc[b][0] + bhh[j];
            float hz = acc[b][1] + bhh[HH + j];
            float hn = acc[b][2] + bhh[2 * HH + j];
            float r = sigf(gx[j] + hr);
            float z = sigf(gx[HH + j] + hz);
            float n = tanhf(gx[2 * HH + j] + r * hn);
            float hv = (1.f - z) * n + z * hin[b * HH + j];
            hout[b * HH + j] = hv;
            we2[((size_t)t * 4 + b) * HH + j] = hv;
        }
    }
}

// ---------------- weekly attention (T=4) ----------------
__global__ void wkatt_k(const float* __restrict__ we2, const float* __restrict__ W,
                        const float* __restrict__ bv, float* __restrict__ wav)
{
    int n = blockIdx.x;
    for (int d = threadIdx.x; d < HH; d += 256) {
        float v[4], l[4];
        #pragma unroll
        for (int tp = 0; tp < 4; tp++) v[tp] = we2[((size_t)n * 4 + tp) * HH + d];
        float mx = -1e30f;
        #pragma unroll
        for (int tp = 0; tp < 4; tp++) {
            float s = bv[tp];
            for (int t2 = 0; t2 < 4; t2++) s += v[t2] * W[tp * 4 + t2];
            l[tp] = s; mx = fmaxf(mx, s);
        }
        float se = 0.f, o = 0.f;
        #pragma unroll
        for (int tp = 0; tp < 4; tp++) {
            float e = expf(l[tp] - mx);
            se += e; o += e * v[tp];
        }
        wav[(size_t)n * HH + d] = o / se;
    }
}

// ---------------- pool attention (C=5, T=20) ----------------
__global__ void poolatt_k(const float* __restrict__ wav, const float* __restrict__ W,
                          const float* __restrict__ bv, float* __restrict__ cat1)
{
    int c = blockIdx.x;
    for (int d = threadIdx.x; d < HH; d += 256) {
        float v[20], l[20];
        for (int t2 = 0; t2 < 20; t2++) v[t2] = wav[((size_t)c * 20 + t2) * HH + d];
        float mx = -1e30f;
        for (int tp = 0; tp < 20; tp++) {
            float s = bv[tp];
            for (int t2 = 0; t2 < 20; t2++) s += v[t2] * W[tp * 20 + t2];
            l[tp] = s; mx = fmaxf(mx, s);
        }
        float se = 0.f, o = 0.f;
        for (int tp = 0; tp < 20; tp++) {
            float e = expf(l[tp] - mx);
            se += e; o += e * v[tp];
        }
        cat1[(size_t)c * HH + d] = o / se;
    }
}

// ---------------- GAT: per-node alpha dots ----------------
__global__ void gat_dots_k(const float* __restrict__ h, const float* __restrict__ as_,
                           const float* __restrict__ ad_, float* __restrict__ ss,
                           float* __restrict__ sd)
{
    int i = blockIdx.x, tid = threadIdx.x;
    float s1 = 0.f, s2 = 0.f;
    for (int k = tid; k < HH; k += 256) {
        float v = h[(size_t)i * HH + k];
        s1 += v * as_[k]; s2 += v * ad_[k];
    }
    __shared__ float r1[256], r2[256];
    r1[tid] = s1; r2[tid] = s2; __syncthreads();
    for (int s = 128; s; s >>= 1) {
        if (tid < s) { r1[tid] += r1[tid + s]; r2[tid] += r2[tid + s]; }
        __syncthreads();
    }
    if (tid == 0) { ss[i] = r1[0]; sd[i] = r2[0]; }
}

// ---------------- GAT aggregate: block per dst node ----------------
#define MAXE 256
__global__ __launch_bounds__(256) void gat_agg_k(
    const float* __restrict__ hmat, const int* __restrict__ esrc,
    const int* __restrict__ edst, int nedges, const float* __restrict__ ss,
    const float* __restrict__ sd, const float* __restrict__ bias, float* __restrict__ outp)
{
    int i = blockIdx.x, tid = threadIdx.x;
    __shared__ int cnt;
    __shared__ int msrc[MAXE];
    __shared__ float mw[MAXE];
    __shared__ float inv_s;
    if (tid == 0) {  // self loop
        cnt = 1; msrc[0] = i;
        float e = ss[i] + sd[i];
        mw[0] = e > 0.f ? e : 0.2f * e;
    }
    __syncthreads();
    for (int e = tid; e < nedges; e += 256) {
        if (edst[e] == i) {
            int p = atomicAdd(&cnt, 1);
            if (p < MAXE) {
                int s = esrc[e];
                msrc[p] = s;
                float v = ss[s] + sd[i];
                mw[p] = v > 0.f ? v : 0.2f * v;
            }
        }
    }
    __syncthreads();
    int m = min(cnt, MAXE);
    if (tid == 0) {
        float mx = -1e30f;
        for (int p = 0; p < m; p++) mx = fmaxf(mx, mw[p]);
        float s = 0.f;
        for (int p = 0; p < m; p++) { float e = expf(mw[p] - mx); mw[p] = e; s += e; }
        inv_s = 1.0f / s;
    }
    __syncthreads();
    for (int d = tid; d < HH; d += 256) {
        float a = 0.f;
        for (int p = 0; p < m; p++) a += mw[p] * hmat[(size_t)msrc[p] * HH + d];
        outp[(size_t)i * HH + d] = a * inv_s + bias[d];
    }
}

// ---------------- concat [wav3, cat, inner] ----------------
__global__ void concat_k(const float* __restrict__ wav, const float* __restrict__ gc,
                         const float* __restrict__ gi, float* __restrict__ cc)
{
    int row = blockIdx.x;
    int c = row / 20;
    for (int k = threadIdx.x; k < H3; k += 256) {
        float v;
        if (k < HH) v = wav[(size_t)row * HH + k];
        else if (k < 2 * HH) v = gc[(size_t)c * HH + (k - HH)];
        else v = gi[(size_t)row * HH + (k - 2 * HH)];
        cc[(size_t)row * H3 + k] = v;
    }
}

// ---------------- reg/cls heads ----------------
__global__ void heads_k(const float* __restrict__ f, const float* __restrict__ regW,
                        const float* __restrict__ regb, const float* __restrict__ clsW,
                        const float* __restrict__ clsb, float* __restrict__ outp)
{
    int i = blockIdx.x, tid = threadIdx.x;
    float s1 = 0.f, s2 = 0.f;
    for (int k = tid; k < HH; k += 256) {
        float v = f[(size_t)i * HH + k];
        s1 += v * regW[k]; s2 += v * clsW[k];
    }
    __shared__ float r1[256], r2[256];
    r1[tid] = s1; r2[tid] = s2; __syncthreads();
    for (int s = 128; s; s >>= 1) {
        if (tid < s) { r1[tid] += r1[tid + s]; r2[tid] += r2[tid + s]; }
        __syncthreads();
    }
    if (tid == 0) {
        outp[i] = r1[0] + regb[0];
        outp[100 + i] = sigf(r2[0] + clsb[0]);
    }
}

extern "C" void kernel_launch(void* const* d_in, const int* in_sizes, int n_in,
                              void* d_out, int out_size, void* d_ws, size_t ws_size,
                              hipStream_t stream)
{
    (void)in_sizes; (void)n_in; (void)out_size; (void)ws_size;
    const float* x0 = (const float*)d_in[0];
    const float* x1 = (const float*)d_in[1];
    const float* x2 = (const float*)d_in[2];
    const float* x3 = (const float*)d_in[3];
    const int*   ie = (const int*)d_in[4];
    const int*   oe = (const int*)d_in[5];
    const float* enc_Wih = (const float*)d_in[6];
    const float* enc_Whh = (const float*)d_in[7];
    const float* enc_bih = (const float*)d_in[8];
    const float* enc_bhh = (const float*)d_in[9];
    const float* enc_attW = (const float*)d_in[10];
    const float* enc_attb = (const float*)d_in[11];
    const float* wk_Wih = (const float*)d_in[12];
    const float* wk_Whh = (const float*)d_in[13];
    const float* wk_bih = (const float*)d_in[14];
    const float* wk_bhh = (const float*)d_in[15];
    const float* wkatt_W = (const float*)d_in[16];
    const float* wkatt_b = (const float*)d_in[17];
    const float* pool_W = (const float*)d_in[18];
    const float* pool_b = (const float*)d_in[19];
    const float* ig_W = (const float*)d_in[20];
    const float* ig_as = (const float*)d_in[21];
    const float* ig_ad = (const float*)d_in[22];
    const float* ig_b = (const float*)d_in[23];
    const float* cg_W = (const float*)d_in[24];
    const float* cg_as = (const float*)d_in[25];
    const float* cg_ad = (const float*)d_in[26];
    const float* cg_b = (const float*)d_in[27];
    const float* fus_W = (const float*)d_in[28];
    const float* fus_b = (const float*)d_in[29];
    const float* reg_W = (const float*)d_in[30];
    const float* reg_b = (const float*)d_in[31];
    const float* cls_W = (const float*)d_in[32];
    const float* cls_b = (const float*)d_in[33];
    float* outp = (float*)d_out;

    // workspace carve-up
    char* p = (char*)d_ws;
    auto alloc = [&](size_t bytes) { char* r = p; p += (bytes + 255) & ~(size_t)255; return (void*)r; };
    float* hA = (float*)alloc((size_t)NW * 128 * HH * 4);
    float* hB = (float*)alloc((size_t)NW * 128 * HH * 4);
    __hip_bfloat16* seq = (__hip_bfloat16*)alloc((size_t)NW * NST * TT * HH * 2);
    float* wex = (float*)alloc((size_t)NW * NST * HH * 4);
    float* gxw = (float*)alloc((size_t)NW * NST * H3 * 4);
    float* hwA = (float*)alloc(4 * HH * 4);
    float* hwB = (float*)alloc(4 * HH * 4);
    float* we2 = (float*)alloc((size_t)NST * 4 * HH * 4);
    float* wav = (float*)alloc((size_t)NST * HH * 4);
    float* hi  = (float*)alloc((size_t)NST * HH * 4);
    float* si_s = (float*)alloc(128 * 4);
    float* si_d = (float*)alloc(128 * 4);
    float* gi  = (float*)alloc((size_t)NST * HH * 4);
    float* cat1 = (float*)alloc(5 * HH * 4);
    float* hc  = (float*)alloc(5 * HH * 4);
    float* sc_s = (float*)alloc(64 * 4);
    float* sc_d = (float*)alloc(64 * 4);
    float* gc  = (float*)alloc(5 * HH * 4);
    float* cc  = (float*)alloc((size_t)NST * H3 * 4);
    float* fbuf = (float*)alloc((size_t)NST * HH * 4);

    // init h=0
    zero_k<<<(NW * 128 * HH + 255) / 256, 256, 0, stream>>>(hA, NW * 128 * HH);
    zero_k<<<(4 * HH + 255) / 256, 256, 0, stream>>>(hwA, 4 * HH);

    // 4-week encoder GRUs, 128 fused steps
    for (int t = 0; t < TT; t++) {
        const float* hin = (t & 1) ? hB : hA;
        float* hout = (t & 1) ? hA : hB;
        enc_step_k<<<dim3(32, 2, NW), 256, 0, stream>>>(
            x0, x1, x2, x3, enc_Wih, enc_Whh, enc_bih, enc_bhh, hin, hout, seq, t);
    }
    // per-week time attention -> wex[w][n][d]
    att1_k<<<dim3(8, NST, NW), 256, 0, stream>>>(seq, enc_attW, enc_attb, wex);

    // weekly GRU input projection (bias folded in)
    gemm_tn_k<0><<<dim3(48, 7), 256, 0, stream>>>(wex, wk_Wih, wk_bih, gxw, 400, H3, HH);
    // weekly GRU recurrence: 100 steps, batch 4
    for (int t = 0; t < NST; t++) {
        const float* hin = (t & 1) ? hwB : hwA;
        float* hout = (t & 1) ? hwA : hwB;
        wk_step_k<<<256, 256, 0, stream>>>(gxw, wk_Whh, wk_bhh, hin, hout, we2, t);
    }
    // weekly attention -> wav (100,1024)
    wkatt_k<<<NST, 256, 0, stream>>>(we2, wkatt_W, wkatt_b, wav);

    // inner GAT
    gemm_tn_k<0><<<dim3(16, 2), 256, 0, stream>>>(wav, ig_W, nullptr, hi, NST, HH, HH);
    gat_dots_k<<<NST, 256, 0, stream>>>(hi, ig_as, ig_ad, si_s, si_d);
    gat_agg_k<<<NST, 256, 0, stream>>>(hi, ie, ie + 2000, 2000, si_s, si_d, ig_b, gi);

    // category pooling attention + outer GAT
    poolatt_k<<<5, 256, 0, stream>>>(wav, pool_W, pool_b, cat1);
    gemm_tn_k<0><<<dim3(16, 1), 256, 0, stream>>>(cat1, cg_W, nullptr, hc, 5, HH, HH);
    gat_dots_k<<<5, 256, 0, stream>>>(hc, cg_as, cg_ad, sc_s, sc_d);
    gat_agg_k<<<5, 256, 0, stream>>>(hc, oe, oe + 25, 25, sc_s, sc_d, cg_b, gc);

    // fusion + heads
    concat_k<<<NST, 256, 0, stream>>>(wav, gc, gi, cc);
    gemm_tn_k<1><<<dim3(16, 2), 256, 0, stream>>>(cc, fus_W, fus_b, fbuf, NST, HH, H3);
    heads_k<<<NST, 256, 0, stream>>>(fbuf, reg_W, reg_b, cls_W, cls_b, outp);
}

// Round 2
// 9585.221 us; speedup vs baseline: 3.6357x; 3.6357x over previous
//
#include <hip/hip_runtime.h>
#include <hip/hip_bf16.h>

#define NW 4
#define NST 100
#define TT 128
#define II 256
#define HH 1024
#define H3 3072

typedef _Float16 h8 __attribute__((ext_vector_type(8)));
typedef float f4 __attribute__((ext_vector_type(4)));
#define LW 40  // LDS row stride in halfs (80B: 16B-aligned, bank-stride 20 -> 2-way only)

__device__ __forceinline__ float sigf(float x) { return 1.0f / (1.0f + expf(-x)); }

// ---------------- zero init ----------------
__global__ void zero_k(float* a, int n) {
    int i = blockIdx.x * 256 + threadIdx.x;
    if (i < n) a[i] = 0.0f;
}

// ---------------- weight concat + fp16 convert: Wc[w][3072][1280] = [Whh | Wih] ----
__global__ void convW_k(const float* __restrict__ Whh, const float* __restrict__ Wih,
                        _Float16* __restrict__ Wc) {
    int col = blockIdx.x * 256 + threadIdx.x;  // 0..1279
    int r = blockIdx.y;                        // 0..3071
    int w = blockIdx.z;
    float v = (col < HH) ? Whh[((size_t)w * H3 + r) * HH + col]
                         : Wih[((size_t)w * H3 + r) * II + (col - HH)];
    Wc[((size_t)w * H3 + r) * 1280 + col] = (_Float16)v;
}

// ---------------- combined bias precompute: bc[w][{r,z,ni,nh}][1024] fp32 ----
__global__ void convB_k(const float* __restrict__ bih, const float* __restrict__ bhh,
                        float* __restrict__ bc) {
    int j = blockIdx.x * 256 + threadIdx.x;
    int w = blockIdx.y;
    const float* bi = bih + w * H3;
    const float* bh = bhh + w * H3;
    float* o = bc + w * 4096;
    o[j] = bi[j] + bh[j];
    o[1024 + j] = bi[1024 + j] + bh[1024 + j];
    o[2048 + j] = bi[2048 + j];
    o[3072 + j] = bh[2048 + j];
}

// ---------------- encoder GRU step, MFMA fp16 ----------------
// grid (32 j-tiles, 4 weeks), block 256 (4 waves). Block tile: 128m x (3g x 32j), K=1280.
__global__ __launch_bounds__(256) void enc2_k(
    const float* __restrict__ x0, const float* __restrict__ x1,
    const float* __restrict__ x2, const float* __restrict__ x3,
    const _Float16* __restrict__ Wc, const float* __restrict__ bc,
    const _Float16* __restrict__ hhin, _Float16* __restrict__ hhout,
    float* __restrict__ h32, _Float16* __restrict__ seq, int t)
{
    int j0 = blockIdx.x * 32;
    int w  = blockIdx.y;
    const float* xw = (w == 0) ? x0 : (w == 1) ? x1 : (w == 2) ? x2 : x3;
    const _Float16* Wcw = Wc + (size_t)w * H3 * 1280;
    const _Float16* hin = hhin + (size_t)w * 128 * HH;
    _Float16* hout = hhout + (size_t)w * 128 * HH;
    float* hw = h32 + (size_t)w * 128 * HH;
    const float* bcw = bc + w * 4096;

    __shared__ _Float16 As[128 * LW];
    __shared__ _Float16 Bs[96 * LW];

    int tid = threadIdx.x;
    int lane = tid & 63, wi = tid >> 6, quad = lane >> 4, l15 = lane & 15;

    f4 aR[2][2] = {}, aZ[2][2] = {}, aNH[2][2] = {}, aNX[2][2] = {};

    // staging assignments
    int ar0 = tid >> 2, aseg = tid & 3;   // A rows 0..63 (+64 for second load)
    int br0 = tid >> 2, bseg = tid & 3;   // B rows 0..63; extra rows 64..95 for tid<128
    int g0 = br0 >> 5, jj0 = br0 & 31;
    int br1 = 64 + (tid >> 2), g1 = br1 >> 5, jj1 = br1 & 31;

    const _Float16* bsrc0 = Wcw + (size_t)((g0 << 10) + j0 + jj0) * 1280 + bseg * 8;
    const _Float16* bsrc1 = Wcw + (size_t)((g1 << 10) + j0 + jj1) * 1280 + bseg * 8;

    // ---- K part 1: hidden (chunks 0..31, k = c*32) ----
    for (int c = 0; c < 32; c++) {
        __syncthreads();
        int kc = c * 32;
        *(uint4*)&As[ar0 * LW + aseg * 8] = *(const uint4*)(hin + (size_t)ar0 * HH + kc + aseg * 8);
        *(uint4*)&As[(ar0 + 64) * LW + aseg * 8] = *(const uint4*)(hin + (size_t)(ar0 + 64) * HH + kc + aseg * 8);
        *(uint4*)&Bs[br0 * LW + bseg * 8] = *(const uint4*)(bsrc0 + kc);
        if (tid < 128)
            *(uint4*)&Bs[br1 * LW + bseg * 8] = *(const uint4*)(bsrc1 + kc);
        __syncthreads();
        h8 af[2], bf[3][2];
        #pragma unroll
        for (int mi = 0; mi < 2; mi++)
            af[mi] = *(const h8*)&As[(wi * 32 + mi * 16 + l15) * LW + quad * 8];
        #pragma unroll
        for (int g = 0; g < 3; g++)
            #pragma unroll
            for (int ji = 0; ji < 2; ji++)
                bf[g][ji] = *(const h8*)&Bs[(g * 32 + ji * 16 + l15) * LW + quad * 8];
        #pragma unroll
        for (int mi = 0; mi < 2; mi++)
            #pragma unroll
            for (int ji = 0; ji < 2; ji++) {
                aR[mi][ji]  = __builtin_amdgcn_mfma_f32_16x16x32_f16(af[mi], bf[0][ji], aR[mi][ji], 0, 0, 0);
                aZ[mi][ji]  = __builtin_amdgcn_mfma_f32_16x16x32_f16(af[mi], bf[1][ji], aZ[mi][ji], 0, 0, 0);
                aNH[mi][ji] = __builtin_amdgcn_mfma_f32_16x16x32_f16(af[mi], bf[2][ji], aNH[mi][ji], 0, 0, 0);
            }
    }
    // ---- K part 2: input x (chunks 32..39), convert fp32->fp16 on stage ----
    for (int c = 32; c < 40; c++) {
        __syncthreads();
        int kc = c * 32;            // Wcat col (1024..1279)
        int kx = kc - 1024;         // x col
        #pragma unroll
        for (int half = 0; half < 2; half++) {
            int row = ar0 + half * 64;
            h8 hv = {};
            if (row < NST) {
                const float* xs = xw + ((size_t)row * TT + t) * II + kx + aseg * 8;
                float4 fa = *(const float4*)xs;
                float4 fb = *(const float4*)(xs + 4);
                hv[0] = (_Float16)fa.x; hv[1] = (_Float16)fa.y;
                hv[2] = (_Float16)fa.z; hv[3] = (_Float16)fa.w;
                hv[4] = (_Float16)fb.x; hv[5] = (_Float16)fb.y;
                hv[6] = (_Float16)fb.z; hv[7] = (_Float16)fb.w;
            }
            *(h8*)&As[row * LW + aseg * 8] = hv;
        }
        *(uint4*)&Bs[br0 * LW + bseg * 8] = *(const uint4*)(bsrc0 + kc);
        if (tid < 128)
            *(uint4*)&Bs[br1 * LW + bseg * 8] = *(const uint4*)(bsrc1 + kc);
        __syncthreads();
        h8 af[2], bf[3][2];
        #pragma unroll
        for (int mi = 0; mi < 2; mi++)
            af[mi] = *(const h8*)&As[(wi * 32 + mi * 16 + l15) * LW + quad * 8];
        #pragma unroll
        for (int g = 0; g < 3; g++)
            #pragma unroll
            for (int ji = 0; ji < 2; ji++)
                bf[g][ji] = *(const h8*)&Bs[(g * 32 + ji * 16 + l15) * LW + quad * 8];
        #pragma unroll
        for (int mi = 0; mi < 2; mi++)
            #pragma unroll
            for (int ji = 0; ji < 2; ji++) {
                aR[mi][ji]  = __builtin_amdgcn_mfma_f32_16x16x32_f16(af[mi], bf[0][ji], aR[mi][ji], 0, 0, 0);
                aZ[mi][ji]  = __builtin_amdgcn_mfma_f32_16x16x32_f16(af[mi], bf[1][ji], aZ[mi][ji], 0, 0, 0);
                aNX[mi][ji] = __builtin_amdgcn_mfma_f32_16x16x32_f16(af[mi], bf[2][ji], aNX[mi][ji], 0, 0, 0);
            }
    }

    // ---- gate epilogue: C/D mapping col=lane&15, row=quad*4+reg ----
    #pragma unroll
    for (int ji = 0; ji < 2; ji++) {
        int j = j0 + ji * 16 + l15;
        float br = bcw[j], bz = bcw[1024 + j], bni = bcw[2048 + j], bnh = bcw[3072 + j];
        #pragma unroll
        for (int mi = 0; mi < 2; mi++) {
            #pragma unroll
            for (int p = 0; p < 4; p++) {
                int row = wi * 32 + mi * 16 + quad * 4 + p;
                float r = sigf(aR[mi][ji][p] + br);
                float z = sigf(aZ[mi][ji][p] + bz);
                float n = tanhf(aNX[mi][ji][p] + bni + r * (aNH[mi][ji][p] + bnh));
                float hp = hw[(size_t)row * HH + j];
                float hv = (1.f - z) * n + z * hp;
                hw[(size_t)row * HH + j] = hv;
                hout[(size_t)row * HH + j] = (_Float16)hv;
                if (row < NST)
                    seq[(((size_t)w * NST + row) * TT + t) * HH + j] = (_Float16)hv;
            }
        }
    }
}

// ---------------- encoder time-attention (fp16 seq) ----------------
__global__ __launch_bounds__(256) void att1_k(
    const _Float16* __restrict__ seq, const float* __restrict__ attW,
    const float* __restrict__ attb, float* __restrict__ wex)
{
    int d0 = blockIdx.x * 128;
    int n  = blockIdx.y;
    int w  = blockIdx.z;
    __shared__ _Float16 S[128][128];  // [t][d]
    __shared__ float PM[16][136];
    int tid = threadIdx.x;
    const _Float16* sp = seq + ((size_t)(w * NST + n) * TT) * HH + d0;
    for (int q = tid; q < 128 * 128; q += 256) {
        int t = q >> 7, d = q & 127;
        S[t][d] = sp[(size_t)t * HH + d];
    }
    __syncthreads();
    int tx = tid & 15, ty = tid >> 4;
    const float* Wg = attW + (size_t)w * TT * TT;
    float acc[8][8];
    #pragma unroll
    for (int i = 0; i < 8; i++) {
        float b = attb[w * TT + ty * 8 + i];
        for (int j = 0; j < 8; j++) acc[i][j] = b;
    }
    for (int t = 0; t < 128; t++) {
        float wv[8], sv[8];
        #pragma unroll
        for (int i = 0; i < 8; i++) wv[i] = Wg[(ty * 8 + i) * TT + t];
        #pragma unroll
        for (int j = 0; j < 8; j++) sv[j] = (float)S[t][tx * 8 + j];
        #pragma unroll
        for (int i = 0; i < 8; i++)
            #pragma unroll
            for (int j = 0; j < 8; j++) acc[i][j] += wv[i] * sv[j];
    }
    float cmax[8], csum[8];
    #pragma unroll
    for (int j = 0; j < 8; j++) {
        float m = acc[0][j];
        for (int i = 1; i < 8; i++) m = fmaxf(m, acc[i][j]);
        PM[ty][tx * 8 + j] = m;
    }
    __syncthreads();
    #pragma unroll
    for (int j = 0; j < 8; j++) {
        float m = -1e30f;
        for (int yy = 0; yy < 16; yy++) m = fmaxf(m, PM[yy][tx * 8 + j]);
        cmax[j] = m;
    }
    __syncthreads();
    #pragma unroll
    for (int j = 0; j < 8; j++) {
        float s = 0.f;
        for (int i = 0; i < 8; i++) { acc[i][j] = expf(acc[i][j] - cmax[j]); s += acc[i][j]; }
        PM[ty][tx * 8 + j] = s;
    }
    __syncthreads();
    #pragma unroll
    for (int j = 0; j < 8; j++) {
        float s = 0.f;
        for (int yy = 0; yy < 16; yy++) s += PM[yy][tx * 8 + j];
        csum[j] = s;
    }
    __syncthreads();
    #pragma unroll
    for (int j = 0; j < 8; j++) {
        float o = 0.f;
        for (int i = 0; i < 8; i++) o += acc[i][j] * (float)S[ty * 8 + i][tx * 8 + j];
        PM[ty][tx * 8 + j] = o;
    }
    __syncthreads();
    if (ty == 0) {
        #pragma unroll
        for (int j = 0; j < 8; j++) {
            float o = 0.f;
            for (int yy = 0; yy < 16; yy++) o += PM[yy][tx * 8 + j];
            wex[((size_t)w * NST + n) * HH + d0 + tx * 8 + j] = o / csum[j];
        }
    }
}

// ---------------- generic fp32 GEMM: C[m][n] = sum_k A[m][k]*B[n][k] (+bias, relu) ----
template <int RELU>
__global__ __launch_bounds__(256) void gemm_tn_k(
    const float* __restrict__ A, const float* __restrict__ B,
    const float* __restrict__ bias, float* __restrict__ C, int M, int N, int K)
{
    int n0 = blockIdx.x * 64, m0 = blockIdx.y * 64;
    __shared__ float As[16][64], Bs[16][64];
    int tid = threadIdx.x, tx = tid & 15, ty = tid >> 4;
    float acc[4][4] = {{0.f}};
    for (int k0 = 0; k0 < K; k0 += 16) {
        __syncthreads();
        for (int q = tid; q < 1024; q += 256) {
            int kk = q & 15, r = q >> 4;
            int m = m0 + r, nn = n0 + r;
            As[kk][r] = (m < M) ? A[(size_t)m * K + k0 + kk] : 0.f;
            Bs[kk][r] = (nn < N) ? B[(size_t)nn * K + k0 + kk] : 0.f;
        }
        __syncthreads();
        #pragma unroll
        for (int kk = 0; kk < 16; kk++) {
            float4 av = *(const float4*)&As[kk][ty * 4];
            float4 bv = *(const float4*)&Bs[kk][tx * 4];
            float a[4] = {av.x, av.y, av.z, av.w};
            float b[4] = {bv.x, bv.y, bv.z, bv.w};
            #pragma unroll
            for (int r = 0; r < 4; r++)
                #pragma unroll
                for (int c = 0; c < 4; c++) acc[r][c] += a[r] * b[c];
        }
    }
    #pragma unroll
    for (int r = 0; r < 4; r++) {
        int m = m0 + ty * 4 + r;
        if (m >= M) continue;
        #pragma unroll
        for (int c = 0; c < 4; c++) {
            int nn = n0 + tx * 4 + c;
            if (nn >= N) continue;
            float v = acc[r][c] + (bias ? bias[nn] : 0.f);
            if (RELU) v = fmaxf(v, 0.f);
            C[(size_t)m * N + nn] = v;
        }
    }
}

// ---------------- weekly GRU step: batch 4, wave per j ----------------
__global__ __launch_bounds__(256) void wk_step_k(
    const float* __restrict__ gxw, const float* __restrict__ Whh,
    const float* __restrict__ bhh, const float* __restrict__ hin,
    float* __restrict__ hout, float* __restrict__ we2, int t)
{
    int j = blockIdx.x * 4 + (threadIdx.x >> 6);
    int lane = threadIdx.x & 63;
    float acc[4][3] = {{0.f}};
    for (int k = lane; k < HH; k += 64) {
        float wr = Whh[(size_t)j * HH + k];
        float wz = Whh[(size_t)(HH + j) * HH + k];
        float wn = Whh[(size_t)(2 * HH + j) * HH + k];
        #pragma unroll
        for (int b = 0; b < 4; b++) {
            float hv = hin[b * HH + k];
            acc[b][0] += hv * wr; acc[b][1] += hv * wz; acc[b][2] += hv * wn;
        }
    }
    #pragma unroll
    for (int b = 0; b < 4; b++)
        #pragma unroll
        for (int g = 0; g < 3; g++)
            for (int o = 32; o; o >>= 1) acc[b][g] += __shfl_down(acc[b][g], o);
    if (lane == 0) {
        for (int b = 0; b < 4; b++) {
            const float* gx = gxw + ((size_t)b * NST + t) * H3;
            float hr = acc[b][0] + bhh[j];
            float hz = acc[b][1] + bhh[HH + j];
            float hn = acc[b][2] + bhh[2 * HH + j];
            float r = sigf(gx[j] + hr);
            float z = sigf(gx[HH + j] + hz);
            float n = tanhf(gx[2 * HH + j] + r * hn);
            float hv = (1.f - z) * n + z * hin[b * HH + j];
            hout[b * HH + j] = hv;
            we2[((size_t)t * 4 + b) * HH + j] = hv;
        }
    }
}

// ---------------- weekly attention (T=4) ----------------
__global__ void wkatt_k(const float* __restrict__ we2, const float* __restrict__ W,
                        const float* __restrict__ bv, float* __restrict__ wav)
{
    int n = blockIdx.x;
    for (int d = threadIdx.x; d < HH; d += 256) {
        float v[4], l[4];
        #pragma unroll
        for (int tp = 0; tp < 4; tp++) v[tp] = we2[((size_t)n * 4 + tp) * HH + d];
        float mx = -1e30f;
        #pragma unroll
        for (int tp = 0; tp < 4; tp++) {
            float s = bv[tp];
            for (int t2 = 0; t2 < 4; t2++) s += v[t2] * W[tp * 4 + t2];
            l[tp] = s; mx = fmaxf(mx, s);
        }
        float se = 0.f, o = 0.f;
        #pragma unroll
        for (int tp = 0; tp < 4; tp++) {
            float e = expf(l[tp] - mx);
            se += e; o += e * v[tp];
        }
        wav[(size_t)n * HH + d] = o / se;
    }
}

// ---------------- pool attention (C=5, T=20) ----------------
__global__ void poolatt_k(const float* __restrict__ wav, const float* __restrict__ W,
                          const float* __restrict__ bv, float* __restrict__ cat1)
{
    int c = blockIdx.x;
    for (int d = threadIdx.x; d < HH; d += 256) {
        float v[20], l[20];
        for (int t2 = 0; t2 < 20; t2++) v[t2] = wav[((size_t)c * 20 + t2) * HH + d];
        float mx = -1e30f;
        for (int tp = 0; tp < 20; tp++) {
            float s = bv[tp];
            for (int t2 = 0; t2 < 20; t2++) s += v[t2] * W[tp * 20 + t2];
            l[tp] = s; mx = fmaxf(mx, s);
        }
        float se = 0.f, o = 0.f;
        for (int tp = 0; tp < 20; tp++) {
            float e = expf(l[tp] - mx);
            se += e; o += e * v[tp];
        }
        cat1[(size_t)c * HH + d] = o / se;
    }
}

// ---------------- GAT: per-node alpha dots ----------------
__global__ void gat_dots_k(const float* __restrict__ h, const float* __restrict__ as_,
                           const float* __restrict__ ad_, float* __restrict__ ss,
                           float* __restrict__ sd)
{
    int i = blockIdx.x, tid = threadIdx.x;
    float s1 = 0.f, s2 = 0.f;
    for (int k = tid; k < HH; k += 256) {
        float v = h[(size_t)i * HH + k];
        s1 += v * as_[k]; s2 += v * ad_[k];
    }
    __shared__ float r1[256], r2[256];
    r1[tid] = s1; r2[tid] = s2; __syncthreads();
    for (int s = 128; s; s >>= 1) {
        if (tid < s) { r1[tid] += r1[tid + s]; r2[tid] += r2[tid + s]; }
        __syncthreads();
    }
    if (tid == 0) { ss[i] = r1[0]; sd[i] = r2[0]; }
}

// ---------------- GAT aggregate: block per dst node ----------------
#define MAXE 256
__global__ __launch_bounds__(256) void gat_agg_k(
    const float* __restrict__ hmat, const int* __restrict__ esrc,
    const int* __restrict__ edst, int nedges, const float* __restrict__ ss,
    const float* __restrict__ sd, const float* __restrict__ bias, float* __restrict__ outp)
{
    int i = blockIdx.x, tid = threadIdx.x;
    __shared__ int cnt;
    __shared__ int msrc[MAXE];
    __shared__ float mw[MAXE];
    __shared__ float inv_s;
    if (tid == 0) {
        cnt = 1; msrc[0] = i;
        float e = ss[i] + sd[i];
        mw[0] = e > 0.f ? e : 0.2f * e;
    }
    __syncthreads();
    for (int e = tid; e < nedges; e += 256) {
        if (edst[e] == i) {
            int p = atomicAdd(&cnt, 1);
            if (p < MAXE) {
                int s = esrc[e];
                msrc[p] = s;
                float v = ss[s] + sd[i];
                mw[p] = v > 0.f ? v : 0.2f * v;
            }
        }
    }
    __syncthreads();
    int m = min(cnt, MAXE);
    if (tid == 0) {
        float mx = -1e30f;
        for (int p = 0; p < m; p++) mx = fmaxf(mx, mw[p]);
        float s = 0.f;
        for (int p = 0; p < m; p++) { float e = expf(mw[p] - mx); mw[p] = e; s += e; }
        inv_s = 1.0f / s;
    }
    __syncthreads();
    for (int d = tid; d < HH; d += 256) {
        float a = 0.f;
        for (int p = 0; p < m; p++) a += mw[p] * hmat[(size_t)msrc[p] * HH + d];
        outp[(size_t)i * HH + d] = a * inv_s + bias[d];
    }
}

// ---------------- concat [wav3, cat, inner] ----------------
__global__ void concat_k(const float* __restrict__ wav, const float* __restrict__ gc,
                         const float* __restrict__ gi, float* __restrict__ cc)
{
    int row = blockIdx.x;
    int c = row / 20;
    for (int k = threadIdx.x; k < H3; k += 256) {
        float v;
        if (k < HH) v = wav[(size_t)row * HH + k];
        else if (k < 2 * HH) v = gc[(size_t)c * HH + (k - HH)];
        else v = gi[(size_t)row * HH + (k - 2 * HH)];
        cc[(size_t)row * H3 + k] = v;
    }
}

// ---------------- reg/cls heads ----------------
__global__ void heads_k(const float* __restrict__ f, const float* __restrict__ regW,
                        const float* __restrict__ regb, const float* __restrict__ clsW,
                        const float* __restrict__ clsb, float* __restrict__ outp)
{
    int i = blockIdx.x, tid = threadIdx.x;
    float s1 = 0.f, s2 = 0.f;
    for (int k = tid; k < HH; k += 256) {
        float v = f[(size_t)i * HH + k];
        s1 += v * regW[k]; s2 += v * clsW[k];
    }
    __shared__ float r1[256], r2[256];
    r1[tid] = s1; r2[tid] = s2; __syncthreads();
    for (int s = 128; s; s >>= 1) {
        if (tid < s) { r1[tid] += r1[tid + s]; r2[tid] += r2[tid + s]; }
        __syncthreads();
    }
    if (tid == 0) {
        outp[i] = r1[0] + regb[0];
        outp[100 + i] = sigf(r2[0] + clsb[0]);
    }
}

extern "C" void kernel_launch(void* const* d_in, const int* in_sizes, int n_in,
                              void* d_out, int out_size, void* d_ws, size_t ws_size,
                              hipStream_t stream)
{
    (void)in_sizes; (void)n_in; (void)out_size; (void)ws_size;
    const float* x0 = (const float*)d_in[0];
    const float* x1 = (const float*)d_in[1];
    const float* x2 = (const float*)d_in[2];
    const float* x3 = (const float*)d_in[3];
    const int*   ie = (const int*)d_in[4];
    const int*   oe = (const int*)d_in[5];
    const float* enc_Wih = (const float*)d_in[6];
    const float* enc_Whh = (const float*)d_in[7];
    const float* enc_bih = (const float*)d_in[8];
    const float* enc_bhh = (const float*)d_in[9];
    const float* enc_attW = (const float*)d_in[10];
    const float* enc_attb = (const float*)d_in[11];
    const float* wk_Wih = (const float*)d_in[12];
    const float* wk_Whh = (const float*)d_in[13];
    const float* wk_bih = (const float*)d_in[14];
    const float* wk_bhh = (const float*)d_in[15];
    const float* wkatt_W = (const float*)d_in[16];
    const float* wkatt_b = (const float*)d_in[17];
    const float* pool_W = (const float*)d_in[18];
    const float* pool_b = (const float*)d_in[19];
    const float* ig_W = (const float*)d_in[20];
    const float* ig_as = (const float*)d_in[21];
    const float* ig_ad = (const float*)d_in[22];
    const float* ig_b = (const float*)d_in[23];
    const float* cg_W = (const float*)d_in[24];
    const float* cg_as = (const float*)d_in[25];
    const float* cg_ad = (const float*)d_in[26];
    const float* cg_b = (const float*)d_in[27];
    const float* fus_W = (const float*)d_in[28];
    const float* fus_b = (const float*)d_in[29];
    const float* reg_W = (const float*)d_in[30];
    const float* reg_b = (const float*)d_in[31];
    const float* cls_W = (const float*)d_in[32];
    const float* cls_b = (const float*)d_in[33];
    float* outp = (float*)d_out;

    // workspace carve-up
    char* p = (char*)d_ws;
    auto alloc = [&](size_t bytes) { char* r = p; p += (bytes + 255) & ~(size_t)255; return (void*)r; };
    _Float16* Wcat = (_Float16*)alloc((size_t)NW * H3 * 1280 * 2);
    float* bc = (float*)alloc((size_t)NW * 4 * HH * 4);
    _Float16* hhA = (_Float16*)alloc((size_t)NW * 128 * HH * 2);
    _Float16* hhB = (_Float16*)alloc((size_t)NW * 128 * HH * 2);
    float* h32 = (float*)alloc((size_t)NW * 128 * HH * 4);
    _Float16* seq = (_Float16*)alloc((size_t)NW * NST * TT * HH * 2);
    float* wex = (float*)alloc((size_t)NW * NST * HH * 4);
    float* gxw = (float*)alloc((size_t)NW * NST * H3 * 4);
    float* hwA = (float*)alloc(4 * HH * 4);
    float* hwB = (float*)alloc(4 * HH * 4);
    float* we2 = (float*)alloc((size_t)NST * 4 * HH * 4);
    float* wav = (float*)alloc((size_t)NST * HH * 4);
    float* hi  = (float*)alloc((size_t)NST * HH * 4);
    float* si_s = (float*)alloc(128 * 4);
    float* si_d = (float*)alloc(128 * 4);
    float* gi  = (float*)alloc((size_t)NST * HH * 4);
    float* cat1 = (float*)alloc(5 * HH * 4);
    float* hc  = (float*)alloc(5 * HH * 4);
    float* sc_s = (float*)alloc(64 * 4);
    float* sc_d = (float*)alloc(64 * 4);
    float* gc  = (float*)alloc(5 * HH * 4);
    float* cc  = (float*)alloc((size_t)NST * H3 * 4);
    float* fbuf = (float*)alloc((size_t)NST * HH * 4);

    // one-time conversions + zero-init
    convW_k<<<dim3(5, H3, NW), 256, 0, stream>>>(enc_Whh, enc_Wih, Wcat);
    convB_k<<<dim3(4, NW), 256, 0, stream>>>(enc_bih, enc_bhh, bc);
    zero_k<<<(NW * 128 * HH + 255) / 256, 256, 0, stream>>>(h32, NW * 128 * HH);
    zero_k<<<(NW * 128 * HH / 2 + 255) / 256, 256, 0, stream>>>((float*)hhA, NW * 128 * HH / 2);
    zero_k<<<(4 * HH + 255) / 256, 256, 0, stream>>>(hwA, 4 * HH);

    // 4-week encoder GRUs, 128 MFMA steps
    for (int t = 0; t < TT; t++) {
        const _Float16* hin = (t & 1) ? hhB : hhA;
        _Float16* hout = (t & 1) ? hhA : hhB;
        enc2_k<<<dim3(32, NW), 256, 0, stream>>>(
            x0, x1, x2, x3, Wcat, bc, hin, hout, h32, seq, t);
    }
    // per-week time attention -> wex[w][n][d]
    att1_k<<<dim3(8, NST, NW), 256, 0, stream>>>(seq, enc_attW, enc_attb, wex);

    // weekly GRU input projection (bias folded in)
    gemm_tn_k<0><<<dim3(48, 7), 256, 0, stream>>>(wex, wk_Wih, wk_bih, gxw, 400, H3, HH);
    // weekly GRU recurrence: 100 steps, batch 4
    for (int t = 0; t < NST; t++) {
        const float* hin = (t & 1) ? hwB : hwA;
        float* hout = (t & 1) ? hwA : hwB;
        wk_step_k<<<256, 256, 0, stream>>>(gxw, wk_Whh, wk_bhh, hin, hout, we2, t);
    }
    // weekly attention -> wav (100,1024)
    wkatt_k<<<NST, 256, 0, stream>>>(we2, wkatt_W, wkatt_b, wav);

    // inner GAT
    gemm_tn_k<0><<<dim3(16, 2), 256, 0, stream>>>(wav, ig_W, nullptr, hi, NST, HH, HH);
    gat_dots_k<<<NST, 256, 0, stream>>>(hi, ig_as, ig_ad, si_s, si_d);
    gat_agg_k<<<NST, 256, 0, stream>>>(hi, ie, ie + 2000, 2000, si_s, si_d, ig_b, gi);

    // category pooling attention + outer GAT
    poolatt_k<<<5, 256, 0, stream>>>(wav, pool_W, pool_b, cat1);
    gemm_tn_k<0><<<dim3(16, 1), 256, 0, stream>>>(cat1, cg_W, nullptr, hc, 5, HH, HH);
    gat_dots_k<<<5, 256, 0, stream>>>(hc, cg_as, cg_ad, sc_s, sc_d);
    gat_agg_k<<<5, 256, 0, stream>>>(hc, oe, oe + 25, 25, sc_s, sc_d, cg_b, gc);

    // fusion + heads
    concat_k<<<NST, 256, 0, stream>>>(wav, gc, gi, cc);
    gemm_tn_k<1><<<dim3(16, 2), 256, 0, stream>>>(cc, fus_W, fus_b, fbuf, NST, HH, H3);
    heads_k<<<NST, 256, 0, stream>>>(fbuf, reg_W, reg_b, cls_W, cls_b, outp);
}

// Round 3
// 5877.287 us; speedup vs baseline: 5.9294x; 1.6309x over previous
//
#include <hip/hip_runtime.h>
#include <hip/hip_bf16.h>

#define NW 4
#define NST 100
#define TT 128
#define II 256
#define HH 1024
#define H3 3072

typedef _Float16 h8 __attribute__((ext_vector_type(8)));
typedef float f4 __attribute__((ext_vector_type(4)));

__device__ __forceinline__ float sigf(float x) { return 1.0f / (1.0f + expf(-x)); }

// ---------------- zero init ----------------
__global__ void zero_k(float* a, int n) {
    int i = blockIdx.x * 256 + threadIdx.x;
    if (i < n) a[i] = 0.0f;
}

// ---------------- weight concat + fp16 convert: Wc[w][3072][1280] = [Whh | Wih] ----
__global__ void convW_k(const float* __restrict__ Whh, const float* __restrict__ Wih,
                        _Float16* __restrict__ Wc) {
    int col = blockIdx.x * 256 + threadIdx.x;  // 0..1279
    int r = blockIdx.y;                        // 0..3071
    int w = blockIdx.z;
    float v = (col < HH) ? Whh[((size_t)w * H3 + r) * HH + col]
                         : Wih[((size_t)w * H3 + r) * II + (col - HH)];
    Wc[((size_t)w * H3 + r) * 1280 + col] = (_Float16)v;
}

// ---------------- weekly weights fp16 ----------------
__global__ void convWk_k(const float* __restrict__ src, _Float16* __restrict__ dst) {
    int col = blockIdx.x * 256 + threadIdx.x;  // 0..1023
    int r = blockIdx.y;                        // 0..3071
    dst[(size_t)r * HH + col] = (_Float16)src[(size_t)r * HH + col];
}

// ---------------- x -> fp16 padded transpose: xT[w][t][128][256] ----------------
__global__ void xcvt_k(const float* __restrict__ x0, const float* __restrict__ x1,
                       const float* __restrict__ x2, const float* __restrict__ x3,
                       _Float16* __restrict__ xT) {
    int idx = blockIdx.x * 256 + threadIdx.x;   // 2^21 total
    int k8 = idx & 31;
    int m  = (idx >> 5) & 127;
    int t  = (idx >> 12) & 127;
    int w  = idx >> 19;
    const float* xw = (w == 0) ? x0 : (w == 1) ? x1 : (w == 2) ? x2 : x3;
    h8 hv = {};
    if (m < NST) {
        const float* s = xw + ((size_t)m * TT + t) * II + k8 * 8;
        float4 fa = *(const float4*)s;
        float4 fb = *(const float4*)(s + 4);
        hv[0] = (_Float16)fa.x; hv[1] = (_Float16)fa.y;
        hv[2] = (_Float16)fa.z; hv[3] = (_Float16)fa.w;
        hv[4] = (_Float16)fb.x; hv[5] = (_Float16)fb.y;
        hv[6] = (_Float16)fb.z; hv[7] = (_Float16)fb.w;
    }
    *(h8*)&xT[(((size_t)w * TT + t) * 128 + m) * II + k8 * 8] = hv;
}

// ---------------- combined bias precompute: bc[w][{r,z,ni,nh}][1024] fp32 ----
__global__ void convB_k(const float* __restrict__ bih, const float* __restrict__ bhh,
                        float* __restrict__ bc) {
    int j = blockIdx.x * 256 + threadIdx.x;
    int w = blockIdx.y;
    const float* bi = bih + w * H3;
    const float* bh = bhh + w * H3;
    float* o = bc + w * 4096;
    o[j] = bi[j] + bh[j];
    o[1024 + j] = bi[1024 + j] + bh[1024 + j];
    o[2048 + j] = bi[2048 + j];
    o[3072 + j] = bh[2048 + j];
}

// ---------------- encoder GRU step, pipelined MFMA fp16 ----------------
// grid (64 j-tiles, 4 weeks), block 256 = 4 waves, each wave m-range 32.
// A-fragments loaded directly global->VGPR; B double-buffered in LDS.
__global__ __launch_bounds__(256) void enc4_k(
    const _Float16* __restrict__ Wc, const float* __restrict__ bc,
    const _Float16* __restrict__ xT,
    const _Float16* __restrict__ hhin, _Float16* __restrict__ hhout,
    float* __restrict__ h32, _Float16* __restrict__ seq, int t)
{
    int j0 = blockIdx.x * 16;
    int w  = blockIdx.y;
    const _Float16* Wcw = Wc + (size_t)w * H3 * 1280;
    const _Float16* hin = hhin + (size_t)w * 128 * HH;
    const _Float16* xt = xT + ((size_t)w * TT + t) * 128 * II;
    _Float16* hout = hhout + (size_t)w * 128 * HH;
    float* hw = h32 + (size_t)w * 128 * HH;
    const float* bcw = bc + w * 4096;

    __shared__ _Float16 Bs[2][48 * 40];   // stride 40 halfs: bank-stride 20 -> 2-way only

    int tid = threadIdx.x;
    int lane = tid & 63, wi = tid >> 6, quad = lane >> 4, l15 = lane & 15;

    // B staging: tid<192, row = tid>>2 (0..47), seg = tid&3 (16B each)
    int brow = tid >> 2, bseg = tid & 3;
    const _Float16* bsrc = Wcw + (size_t)((brow >> 4) * 1024 + j0 + (brow & 15)) * 1280 + bseg * 8;

    // A-fragment base pointers (lane-resolved): row = wi*32 + mi*16 + l15
    const _Float16* pA0h = hin + (size_t)(wi * 32 + l15) * HH + quad * 8;
    const _Float16* pA1h = hin + (size_t)(wi * 32 + 16 + l15) * HH + quad * 8;
    const _Float16* pA0x = xt + (size_t)(wi * 32 + l15) * II + quad * 8;
    const _Float16* pA1x = xt + (size_t)(wi * 32 + 16 + l15) * II + quad * 8;

    f4 aR[2] = {}, aZ[2] = {}, aNH[2] = {}, aNX[2] = {};

    // preload chunk 0
    uint4 breg = {};
    if (tid < 192) breg = *(const uint4*)(bsrc);
    h8 a0 = *(const h8*)(pA0h);
    h8 a1 = *(const h8*)(pA1h);
    if (tid < 192) *(uint4*)&Bs[0][brow * 40 + bseg * 8] = breg;
    __syncthreads();

    for (int c = 0; c < 40; c++) {
        int buf = c & 1;
        // prefetch chunk c+1 (global -> regs) while computing c
        uint4 bnext = {};
        h8 an0 = {}, an1 = {};
        if (c < 39) {
            int cn = c + 1;
            if (tid < 192) bnext = *(const uint4*)(bsrc + cn * 32);
            const _Float16* s0 = (cn < 32) ? pA0h + cn * 32 : pA0x + (cn - 32) * 32;
            const _Float16* s1 = (cn < 32) ? pA1h + cn * 32 : pA1x + (cn - 32) * 32;
            an0 = *(const h8*)s0;
            an1 = *(const h8*)s1;
        }
        // B fragments from LDS
        h8 bf0 = *(const h8*)&Bs[buf][(l15) * 40 + quad * 8];
        h8 bf1 = *(const h8*)&Bs[buf][(16 + l15) * 40 + quad * 8];
        h8 bf2 = *(const h8*)&Bs[buf][(32 + l15) * 40 + quad * 8];
        // MFMA
        aR[0] = __builtin_amdgcn_mfma_f32_16x16x32_f16(a0, bf0, aR[0], 0, 0, 0);
        aR[1] = __builtin_amdgcn_mfma_f32_16x16x32_f16(a1, bf0, aR[1], 0, 0, 0);
        aZ[0] = __builtin_amdgcn_mfma_f32_16x16x32_f16(a0, bf1, aZ[0], 0, 0, 0);
        aZ[1] = __builtin_amdgcn_mfma_f32_16x16x32_f16(a1, bf1, aZ[1], 0, 0, 0);
        if (c < 32) {
            aNH[0] = __builtin_amdgcn_mfma_f32_16x16x32_f16(a0, bf2, aNH[0], 0, 0, 0);
            aNH[1] = __builtin_amdgcn_mfma_f32_16x16x32_f16(a1, bf2, aNH[1], 0, 0, 0);
        } else {
            aNX[0] = __builtin_amdgcn_mfma_f32_16x16x32_f16(a0, bf2, aNX[0], 0, 0, 0);
            aNX[1] = __builtin_amdgcn_mfma_f32_16x16x32_f16(a1, bf2, aNX[1], 0, 0, 0);
        }
        // stash next B chunk into the other buffer
        if (c < 39 && tid < 192)
            *(uint4*)&Bs[buf ^ 1][brow * 40 + bseg * 8] = bnext;
        __syncthreads();
        a0 = an0; a1 = an1;
    }

    // ---- gate epilogue: C/D mapping col=lane&15, row=quad*4+reg ----
    int j = j0 + l15;
    float br = bcw[j], bz = bcw[1024 + j], bni = bcw[2048 + j], bnh = bcw[3072 + j];
    #pragma unroll
    for (int mi = 0; mi < 2; mi++) {
        #pragma unroll
        for (int p = 0; p < 4; p++) {
            int row = wi * 32 + mi * 16 + quad * 4 + p;
            float r = sigf(aR[mi][p] + br);
            float z = sigf(aZ[mi][p] + bz);
            float n = tanhf(aNX[mi][p] + bni + r * (aNH[mi][p] + bnh));
            float hp = hw[(size_t)row * HH + j];
            float hv = (1.f - z) * n + z * hp;
            hw[(size_t)row * HH + j] = hv;
            hout[(size_t)row * HH + j] = (_Float16)hv;
            if (row < NST)
                seq[(((size_t)w * NST + row) * TT + t) * HH + j] = (_Float16)hv;
        }
    }
}

// ---------------- encoder time-attention (fp16 seq, vectorized) ----------------
__global__ __launch_bounds__(256) void att1_k(
    const _Float16* __restrict__ seq, const float* __restrict__ attW,
    const float* __restrict__ attb, float* __restrict__ wex)
{
    int d0 = blockIdx.x * 128;
    int n  = blockIdx.y;
    int w  = blockIdx.z;
    __shared__ _Float16 S[128][128];  // [t][d]
    __shared__ float PM[16][136];
    int tid = threadIdx.x;
    const _Float16* sp = seq + ((size_t)(w * NST + n) * TT) * HH + d0;
    for (int q = tid; q < 2048; q += 256) {
        int t = q >> 4, seg = q & 15;
        *(h8*)&S[t][seg * 8] = *(const h8*)(sp + (size_t)t * HH + seg * 8);
    }
    __syncthreads();
    int tx = tid & 15, ty = tid >> 4;
    const float* Wg = attW + (size_t)w * TT * TT;
    float acc[8][8];
    #pragma unroll
    for (int i = 0; i < 8; i++) {
        float b = attb[w * TT + ty * 8 + i];
        for (int j = 0; j < 8; j++) acc[i][j] = b;
    }
    for (int t = 0; t < 128; t++) {
        float wv[8], sv[8];
        #pragma unroll
        for (int i = 0; i < 8; i++) wv[i] = Wg[(ty * 8 + i) * TT + t];
        h8 s8 = *(const h8*)&S[t][tx * 8];
        #pragma unroll
        for (int j = 0; j < 8; j++) sv[j] = (float)s8[j];
        #pragma unroll
        for (int i = 0; i < 8; i++)
            #pragma unroll
            for (int j = 0; j < 8; j++) acc[i][j] += wv[i] * sv[j];
    }
    float cmax[8], csum[8];
    #pragma unroll
    for (int j = 0; j < 8; j++) {
        float m = acc[0][j];
        for (int i = 1; i < 8; i++) m = fmaxf(m, acc[i][j]);
        PM[ty][tx * 8 + j] = m;
    }
    __syncthreads();
    #pragma unroll
    for (int j = 0; j < 8; j++) {
        float m = -1e30f;
        for (int yy = 0; yy < 16; yy++) m = fmaxf(m, PM[yy][tx * 8 + j]);
        cmax[j] = m;
    }
    __syncthreads();
    #pragma unroll
    for (int j = 0; j < 8; j++) {
        float s = 0.f;
        for (int i = 0; i < 8; i++) { acc[i][j] = expf(acc[i][j] - cmax[j]); s += acc[i][j]; }
        PM[ty][tx * 8 + j] = s;
    }
    __syncthreads();
    #pragma unroll
    for (int j = 0; j < 8; j++) {
        float s = 0.f;
        for (int yy = 0; yy < 16; yy++) s += PM[yy][tx * 8 + j];
        csum[j] = s;
    }
    __syncthreads();
    #pragma unroll
    for (int i = 0; i < 8; i++) {
        h8 s8 = *(const h8*)&S[ty * 8 + i][tx * 8];
        #pragma unroll
        for (int j = 0; j < 8; j++) {
            if (i == 0) PM[ty][tx * 8 + j] = 0.f;
            PM[ty][tx * 8 + j] += acc[i][j] * (float)s8[j];
        }
    }
    __syncthreads();
    if (ty == 0) {
        #pragma unroll
        for (int j = 0; j < 8; j++) {
            float o = 0.f;
            for (int yy = 0; yy < 16; yy++) o += PM[yy][tx * 8 + j];
            wex[((size_t)w * NST + n) * HH + d0 + tx * 8 + j] = o / csum[j];
        }
    }
}

// ---------------- generic fp32 GEMM: C[m][n] = sum_k A[m][k]*B[n][k] (+bias, relu) ----
template <int RELU>
__global__ __launch_bounds__(256) void gemm_tn_k(
    const float* __restrict__ A, const float* __restrict__ B,
    const float* __restrict__ bias, float* __restrict__ C, int M, int N, int K)
{
    int n0 = blockIdx.x * 64, m0 = blockIdx.y * 64;
    __shared__ float As[16][64], Bs[16][64];
    int tid = threadIdx.x, tx = tid & 15, ty = tid >> 4;
    float acc[4][4] = {{0.f}};
    for (int k0 = 0; k0 < K; k0 += 16) {
        __syncthreads();
        for (int q = tid; q < 1024; q += 256) {
            int kk = q & 15, r = q >> 4;
            int m = m0 + r, nn = n0 + r;
            As[kk][r] = (m < M) ? A[(size_t)m * K + k0 + kk] : 0.f;
            Bs[kk][r] = (nn < N) ? B[(size_t)nn * K + k0 + kk] : 0.f;
        }
        __syncthreads();
        #pragma unroll
        for (int kk = 0; kk < 16; kk++) {
            float4 av = *(const float4*)&As[kk][ty * 4];
            float4 bv = *(const float4*)&Bs[kk][tx * 4];
            float a[4] = {av.x, av.y, av.z, av.w};
            float b[4] = {bv.x, bv.y, bv.z, bv.w};
            #pragma unroll
            for (int r = 0; r < 4; r++)
                #pragma unroll
                for (int c = 0; c < 4; c++) acc[r][c] += a[r] * b[c];
        }
    }
    #pragma unroll
    for (int r = 0; r < 4; r++) {
        int m = m0 + ty * 4 + r;
        if (m >= M) continue;
        #pragma unroll
        for (int c = 0; c < 4; c++) {
            int nn = n0 + tx * 4 + c;
            if (nn >= N) continue;
            float v = acc[r][c] + (bias ? bias[nn] : 0.f);
            if (RELU) v = fmaxf(v, 0.f);
            C[(size_t)m * N + nn] = v;
        }
    }
}

// ---------------- weekly GRU step: batch 4, wave per j, fp16 weights ----------------
__global__ __launch_bounds__(256) void wk_step2_k(
    const float* __restrict__ gxw, const _Float16* __restrict__ wkW,
    const float* __restrict__ bhh, const float* __restrict__ hin,
    float* __restrict__ hout, float* __restrict__ we2, int t)
{
    int wi = threadIdx.x >> 6, lane = threadIdx.x & 63;
    int j = blockIdx.x * 4 + wi;
    int k0 = lane * 16;
    float wf[3][16];
    #pragma unroll
    for (int g = 0; g < 3; g++) {
        h8 wa = *(const h8*)&wkW[(size_t)(g * HH + j) * HH + k0];
        h8 wb = *(const h8*)&wkW[(size_t)(g * HH + j) * HH + k0 + 8];
        #pragma unroll
        for (int i = 0; i < 8; i++) { wf[g][i] = (float)wa[i]; wf[g][8 + i] = (float)wb[i]; }
    }
    float acc[4][3] = {};
    #pragma unroll
    for (int b = 0; b < 4; b++) {
        float hv[16];
        #pragma unroll
        for (int s = 0; s < 4; s++) {
            float4 hq = *(const float4*)&hin[b * HH + k0 + s * 4];
            hv[s * 4] = hq.x; hv[s * 4 + 1] = hq.y; hv[s * 4 + 2] = hq.z; hv[s * 4 + 3] = hq.w;
        }
        #pragma unroll
        for (int g = 0; g < 3; g++)
            #pragma unroll
            for (int i = 0; i < 16; i++) acc[b][g] += wf[g][i] * hv[i];
    }
    #pragma unroll
    for (int b = 0; b < 4; b++)
        #pragma unroll
        for (int g = 0; g < 3; g++)
            for (int o = 32; o; o >>= 1) acc[b][g] += __shfl_down(acc[b][g], o);
    if (lane == 0) {
        for (int b = 0; b < 4; b++) {
            const float* gx = gxw + ((size_t)b * NST + t) * H3;
            float hr = acc[b][0] + bhh[j];
            float hz = acc[b][1] + bhh[HH + j];
            float hn = acc[b][2] + bhh[2 * HH + j];
            float r = sigf(gx[j] + hr);
            float z = sigf(gx[HH + j] + hz);
            float n = tanhf(gx[2 * HH + j] + r * hn);
            float hv = (1.f - z) * n + z * hin[b * HH + j];
            hout[b * HH + j] = hv;
            we2[((size_t)t * 4 + b) * HH + j] = hv;
        }
    }
}

// ---------------- weekly attention (T=4) ----------------
__global__ void wkatt_k(const float* __restrict__ we2, const float* __restrict__ W,
                        const float* __restrict__ bv, float* __restrict__ wav)
{
    int n = blockIdx.x;
    for (int d = threadIdx.x; d < HH; d += 256) {
        float v[4], l[4];
        #pragma unroll
        for (int tp = 0; tp < 4; tp++) v[tp] = we2[((size_t)n * 4 + tp) * HH + d];
        float mx = -1e30f;
        #pragma unroll
        for (int tp = 0; tp < 4; tp++) {
            float s = bv[tp];
            for (int t2 = 0; t2 < 4; t2++) s += v[t2] * W[tp * 4 + t2];
            l[tp] = s; mx = fmaxf(mx, s);
        }
        float se = 0.f, o = 0.f;
        #pragma unroll
        for (int tp = 0; tp < 4; tp++) {
            float e = expf(l[tp] - mx);
            se += e; o += e * v[tp];
        }
        wav[(size_t)n * HH + d] = o / se;
    }
}

// ---------------- pool attention (C=5, T=20) ----------------
__global__ void poolatt_k(const float* __restrict__ wav, const float* __restrict__ W,
                          const float* __restrict__ bv, float* __restrict__ cat1)
{
    int c = blockIdx.x;
    for (int d = threadIdx.x; d < HH; d += 256) {
        float v[20], l[20];
        for (int t2 = 0; t2 < 20; t2++) v[t2] = wav[((size_t)c * 20 + t2) * HH + d];
        float mx = -1e30f;
        for (int tp = 0; tp < 20; tp++) {
            float s = bv[tp];
            for (int t2 = 0; t2 < 20; t2++) s += v[t2] * W[tp * 20 + t2];
            l[tp] = s; mx = fmaxf(mx, s);
        }
        float se = 0.f, o = 0.f;
        for (int tp = 0; tp < 20; tp++) {
            float e = expf(l[tp] - mx);
            se += e; o += e * v[tp];
        }
        cat1[(size_t)c * HH + d] = o / se;
    }
}

// ---------------- GAT: per-node alpha dots ----------------
__global__ void gat_dots_k(const float* __restrict__ h, const float* __restrict__ as_,
                           const float* __restrict__ ad_, float* __restrict__ ss,
                           float* __restrict__ sd)
{
    int i = blockIdx.x, tid = threadIdx.x;
    float s1 = 0.f, s2 = 0.f;
    for (int k = tid; k < HH; k += 256) {
        float v = h[(size_t)i * HH + k];
        s1 += v * as_[k]; s2 += v * ad_[k];
    }
    __shared__ float r1[256], r2[256];
    r1[tid] = s1; r2[tid] = s2; __syncthreads();
    for (int s = 128; s; s >>= 1) {
        if (tid < s) { r1[tid] += r1[tid + s]; r2[tid] += r2[tid + s]; }
        __syncthreads();
    }
    if (tid == 0) { ss[i] = r1[0]; sd[i] = r2[0]; }
}

// ---------------- GAT aggregate: block per dst node ----------------
#define MAXE 256
__global__ __launch_bounds__(256) void gat_agg_k(
    const float* __restrict__ hmat, const int* __restrict__ esrc,
    const int* __restrict__ edst, int nedges, const float* __restrict__ ss,
    const float* __restrict__ sd, const float* __restrict__ bias, float* __restrict__ outp)
{
    int i = blockIdx.x, tid = threadIdx.x;
    __shared__ int cnt;
    __shared__ int msrc[MAXE];
    __shared__ float mw[MAXE];
    __shared__ float inv_s;
    if (tid == 0) {
        cnt = 1; msrc[0] = i;
        float e = ss[i] + sd[i];
        mw[0] = e > 0.f ? e : 0.2f * e;
    }
    __syncthreads();
    for (int e = tid; e < nedges; e += 256) {
        if (edst[e] == i) {
            int p = atomicAdd(&cnt, 1);
            if (p < MAXE) {
                int s = esrc[e];
                msrc[p] = s;
                float v = ss[s] + sd[i];
                mw[p] = v > 0.f ? v : 0.2f * v;
            }
        }
    }
    __syncthreads();
    int m = min(cnt, MAXE);
    if (tid == 0) {
        float mx = -1e30f;
        for (int p = 0; p < m; p++) mx = fmaxf(mx, mw[p]);
        float s = 0.f;
        for (int p = 0; p < m; p++) { float e = expf(mw[p] - mx); mw[p] = e; s += e; }
        inv_s = 1.0f / s;
    }
    __syncthreads();
    for (int d = tid; d < HH; d += 256) {
        float a = 0.f;
        for (int p = 0; p < m; p++) a += mw[p] * hmat[(size_t)msrc[p] * HH + d];
        outp[(size_t)i * HH + d] = a * inv_s + bias[d];
    }
}

// ---------------- concat [wav3, cat, inner] ----------------
__global__ void concat_k(const float* __restrict__ wav, const float* __restrict__ gc,
                         const float* __restrict__ gi, float* __restrict__ cc)
{
    int row = blockIdx.x;
    int c = row / 20;
    for (int k = threadIdx.x; k < H3; k += 256) {
        float v;
        if (k < HH) v = wav[(size_t)row * HH + k];
        else if (k < 2 * HH) v = gc[(size_t)c * HH + (k - HH)];
        else v = gi[(size_t)row * HH + (k - 2 * HH)];
        cc[(size_t)row * H3 + k] = v;
    }
}

// ---------------- reg/cls heads ----------------
__global__ void heads_k(const float* __restrict__ f, const float* __restrict__ regW,
                        const float* __restrict__ regb, const float* __restrict__ clsW,
                        const float* __restrict__ clsb, float* __restrict__ outp)
{
    int i = blockIdx.x, tid = threadIdx.x;
    float s1 = 0.f, s2 = 0.f;
    for (int k = tid; k < HH; k += 256) {
        float v = f[(size_t)i * HH + k];
        s1 += v * regW[k]; s2 += v * clsW[k];
    }
    __shared__ float r1[256], r2[256];
    r1[tid] = s1; r2[tid] = s2; __syncthreads();
    for (int s = 128; s; s >>= 1) {
        if (tid < s) { r1[tid] += r1[tid + s]; r2[tid] += r2[tid + s]; }
        __syncthreads();
    }
    if (tid == 0) {
        outp[i] = r1[0] + regb[0];
        outp[100 + i] = sigf(r2[0] + clsb[0]);
    }
}

extern "C" void kernel_launch(void* const* d_in, const int* in_sizes, int n_in,
                              void* d_out, int out_size, void* d_ws, size_t ws_size,
                              hipStream_t stream)
{
    (void)in_sizes; (void)n_in; (void)out_size; (void)ws_size;
    const float* x0 = (const float*)d_in[0];
    const float* x1 = (const float*)d_in[1];
    const float* x2 = (const float*)d_in[2];
    const float* x3 = (const float*)d_in[3];
    const int*   ie = (const int*)d_in[4];
    const int*   oe = (const int*)d_in[5];
    const float* enc_Wih = (const float*)d_in[6];
    const float* enc_Whh = (const float*)d_in[7];
    const float* enc_bih = (const float*)d_in[8];
    const float* enc_bhh = (const float*)d_in[9];
    const float* enc_attW = (const float*)d_in[10];
    const float* enc_attb = (const float*)d_in[11];
    const float* wk_Wih = (const float*)d_in[12];
    const float* wk_Whh = (const float*)d_in[13];
    const float* wk_bih = (const float*)d_in[14];
    const float* wk_bhh = (const float*)d_in[15];
    const float* wkatt_W = (const float*)d_in[16];
    const float* wkatt_b = (const float*)d_in[17];
    const float* pool_W = (const float*)d_in[18];
    const float* pool_b = (const float*)d_in[19];
    const float* ig_W = (const float*)d_in[20];
    const float* ig_as = (const float*)d_in[21];
    const float* ig_ad = (const float*)d_in[22];
    const float* ig_b = (const float*)d_in[23];
    const float* cg_W = (const float*)d_in[24];
    const float* cg_as = (const float*)d_in[25];
    const float* cg_ad = (const float*)d_in[26];
    const float* cg_b = (const float*)d_in[27];
    const float* fus_W = (const float*)d_in[28];
    const float* fus_b = (const float*)d_in[29];
    const float* reg_W = (const float*)d_in[30];
    const float* reg_b = (const float*)d_in[31];
    const float* cls_W = (const float*)d_in[32];
    const float* cls_b = (const float*)d_in[33];
    float* outp = (float*)d_out;

    // workspace carve-up
    char* p = (char*)d_ws;
    auto alloc = [&](size_t bytes) { char* r = p; p += (bytes + 255) & ~(size_t)255; return (void*)r; };
    _Float16* Wcat = (_Float16*)alloc((size_t)NW * H3 * 1280 * 2);
    float* bc = (float*)alloc((size_t)NW * 4 * HH * 4);
    _Float16* wkW = (_Float16*)alloc((size_t)H3 * HH * 2);
    _Float16* xT = (_Float16*)alloc((size_t)NW * TT * 128 * II * 2);
    _Float16* hhA = (_Float16*)alloc((size_t)NW * 128 * HH * 2);
    _Float16* hhB = (_Float16*)alloc((size_t)NW * 128 * HH * 2);
    float* h32 = (float*)alloc((size_t)NW * 128 * HH * 4);
    _Float16* seq = (_Float16*)alloc((size_t)NW * NST * TT * HH * 2);
    float* wex = (float*)alloc((size_t)NW * NST * HH * 4);
    float* gxw = (float*)alloc((size_t)NW * NST * H3 * 4);
    float* hwA = (float*)alloc(4 * HH * 4);
    float* hwB = (float*)alloc(4 * HH * 4);
    float* we2 = (float*)alloc((size_t)NST * 4 * HH * 4);
    float* wav = (float*)alloc((size_t)NST * HH * 4);
    float* hi  = (float*)alloc((size_t)NST * HH * 4);
    float* si_s = (float*)alloc(128 * 4);
    float* si_d = (float*)alloc(128 * 4);
    float* gi  = (float*)alloc((size_t)NST * HH * 4);
    float* cat1 = (float*)alloc(5 * HH * 4);
    float* hc  = (float*)alloc(5 * HH * 4);
    float* sc_s = (float*)alloc(64 * 4);
    float* sc_d = (float*)alloc(64 * 4);
    float* gc  = (float*)alloc(5 * HH * 4);
    float* cc  = (float*)alloc((size_t)NST * H3 * 4);
    float* fbuf = (float*)alloc((size_t)NST * HH * 4);

    // one-time conversions + zero-init
    convW_k<<<dim3(5, H3, NW), 256, 0, stream>>>(enc_Whh, enc_Wih, Wcat);
    convB_k<<<dim3(4, NW), 256, 0, stream>>>(enc_bih, enc_bhh, bc);
    convWk_k<<<dim3(4, H3), 256, 0, stream>>>(wk_Whh, wkW);
    xcvt_k<<<8192, 256, 0, stream>>>(x0, x1, x2, x3, xT);
    zero_k<<<(NW * 128 * HH + 255) / 256, 256, 0, stream>>>(h32, NW * 128 * HH);
    zero_k<<<(NW * 128 * HH / 2 + 255) / 256, 256, 0, stream>>>((float*)hhA, NW * 128 * HH / 2);
    zero_k<<<(4 * HH + 255) / 256, 256, 0, stream>>>(hwA, 4 * HH);

    // 4-week encoder GRUs, 128 pipelined MFMA steps
    for (int t = 0; t < TT; t++) {
        const _Float16* hin = (t & 1) ? hhB : hhA;
        _Float16* hout = (t & 1) ? hhA : hhB;
        enc4_k<<<dim3(64, NW), 256, 0, stream>>>(
            Wcat, bc, xT, hin, hout, h32, seq, t);
    }
    // per-week time attention -> wex[w][n][d]
    att1_k<<<dim3(8, NST, NW), 256, 0, stream>>>(seq, enc_attW, enc_attb, wex);

    // weekly GRU input projection (bias folded in)
    gemm_tn_k<0><<<dim3(48, 7), 256, 0, stream>>>(wex, wk_Wih, wk_bih, gxw, 400, H3, HH);
    // weekly GRU recurrence: 100 steps, batch 4
    for (int t = 0; t < NST; t++) {
        const float* hin = (t & 1) ? hwB : hwA;
        float* hout = (t & 1) ? hwA : hwB;
        wk_step2_k<<<256, 256, 0, stream>>>(gxw, wkW, wk_bhh, hin, hout, we2, t);
    }
    // weekly attention -> wav (100,1024)
    wkatt_k<<<NST, 256, 0, stream>>>(we2, wkatt_W, wkatt_b, wav);

    // inner GAT
    gemm_tn_k<0><<<dim3(16, 2), 256, 0, stream>>>(wav, ig_W, nullptr, hi, NST, HH, HH);
    gat_dots_k<<<NST, 256, 0, stream>>>(hi, ig_as, ig_ad, si_s, si_d);
    gat_agg_k<<<NST, 256, 0, stream>>>(hi, ie, ie + 2000, 2000, si_s, si_d, ig_b, gi);

    // category pooling attention + outer GAT
    poolatt_k<<<5, 256, 0, stream>>>(wav, pool_W, pool_b, cat1);
    gemm_tn_k<0><<<dim3(16, 1), 256, 0, stream>>>(cat1, cg_W, nullptr, hc, 5, HH, HH);
    gat_dots_k<<<5, 256, 0, stream>>>(hc, cg_as, cg_ad, sc_s, sc_d);
    gat_agg_k<<<5, 256, 0, stream>>>(hc, oe, oe + 25, 25, sc_s, sc_d, cg_b, gc);

    // fusion + heads
    concat_k<<<NST, 256, 0, stream>>>(wav, gc, gi, cc);
    gemm_tn_k<1><<<dim3(16, 2), 256, 0, stream>>>(cc, fus_W, fus_b, fbuf, NST, HH, H3);
    heads_k<<<NST, 256, 0, stream>>>(fbuf, reg_W, reg_b, cls_W, cls_b, outp);
}